// Round 13
// baseline (13.195 us; speedup 1.0000x reference)
//
#include <hip/hip_runtime.h>
#include <hip/hip_bf16.h>
#include <math.h>

#define HEADS 8
#define BATCH 4
#define SEQ 2048
#define CDIM 32
#define WINDOW 10

#define RPB 128                // rows per block: 2 phases x 64 rows
#define PBAND 96               // band rows staged per phase
#define VSTR 20                // u32 stride of packed V rows (16 + 4 pad)

typedef float f32x4 __attribute__((ext_vector_type(4)));
typedef short s16x8 __attribute__((ext_vector_type(8)));
#define MFMA16 __builtin_amdgcn_mfma_f32_16x16x32_bf16

union BF8 { s16x8 v; __hip_bfloat162 h[4]; };
union U32 { __hip_bfloat162 h; unsigned u; };
union U4  { unsigned u[4]; s16x8 v; };

// R9's verified MFMA core (swapped PV with shared slot->k bijection, packed V,
// max-free log2 softmax, per-wave ballots) + a 2-phase double-buffered memory
// schedule: all global loads for BOTH phases issue up front, so each block
// pays one memory-latency window per 128 rows and phase-1 staging completes
// under phase-0 compute.
__global__ __launch_bounds__(256) void lwin_attn_kernel(
    const float* __restrict__ Q, const float* __restrict__ K,
    const float* __restrict__ V, const float* __restrict__ G,
    const unsigned char* __restrict__ seqMask, float* __restrict__ out)
{
    __shared__ short    K_s[2][PBAND * 32];     // bf16 K bands, row-major
    __shared__ unsigned V_s[2][PBAND * VSTR];   // packed (ch c, ch c+16) pairs

    // XCD-aware swizzle (512 blocks, 64 per XCD chunk)
    const int d = blockIdx.x;
    const int b = (d & 7) * 64 + (d >> 3);

    const int hn = b >> 4;                      // h*BATCH + n (16 blocks per hn)
    const int s0 = (b & 15) * RPB;
    const int n  = hn & 3;
    const int h  = hn >> 2;
    const int base_hn = hn * SEQ * CDIM;

    const int tid  = threadIdx.x;
    const int w    = tid >> 6;                  // wave = tile index 0..3
    const int lane = tid & 63;
    const int q    = lane & 15;                 // query-in-tile / MFMA N-col
    const int g    = lane >> 4;                 // lane group

    // ---- issue ALL staging loads (both phases) up front: 768 tasks/phase,
    // 3 per thread (tasks 0..383 = K octets, 384..767 = V quads) ----
    float4 ld[2][3][2];
#pragma unroll
    for (int p = 0; p < 2; ++p) {
        const int sp = s0 + 64 * p;
#pragma unroll
        for (int k = 0; k < 3; ++k) {
            const int id = tid + 256 * k;
            const bool isK = id < 384;
            const int tt = isK ? id : id - 384;
            const int i = tt >> 2, o = tt & 3;
            const int t  = sp - 16 + i;
            const int tc = min(max(t, 0), SEQ - 1);
            const float* src = (isK ? K : V) + base_hn + tc * 32;
            const int off0 = isK ? 8 * o : 4 * o;
            const int off1 = isK ? 8 * o + 4 : 16 + 4 * o;
            ld[p][k][0] = *(const float4*)&src[off0];
            ld[p][k][1] = *(const float4*)&src[off1];
        }
    }

    // ---- Q (scaled->bf16), G, seqMask ballots for both phases ----
    const float sc = 0.17677669529663687f * 1.4426950408889634f; // 1/sqrt(32)*log2e
    BF8 bq[2];
    float4 gA[2], gB[2];
    unsigned long long mI[2];
#pragma unroll
    for (int p = 0; p < 2; ++p) {
        const int sw   = s0 + 64 * p + 16 * w;
        const int rowq = hn * SEQ + sw + q;
        const float4 q0 = *(const float4*)&Q[rowq * 32 + 8 * g];
        const float4 q1 = *(const float4*)&Q[rowq * 32 + 8 * g + 4];
        bq[p].h[0] = __float22bfloat162_rn(make_float2(q0.x * sc, q0.y * sc));
        bq[p].h[1] = __float22bfloat162_rn(make_float2(q0.z * sc, q0.w * sc));
        bq[p].h[2] = __float22bfloat162_rn(make_float2(q1.x * sc, q1.y * sc));
        bq[p].h[3] = __float22bfloat162_rn(make_float2(q1.z * sc, q1.w * sc));
        gA[p] = *(const float4*)&G[rowq * 32 + 4 * g];
        gB[p] = *(const float4*)&G[rowq * 32 + 16 + 4 * g];
        const int t  = sw - 16 + lane;
        const int tc = min(max(t, 0), SEQ - 1);
        const bool inval = (t < 0) || (t >= SEQ) || (seqMask[n * SEQ + tc] != 0);
        mI[p] = __ballot(inval);
    }

    // ---- cvt + LDS write for one phase's staged registers ----
    auto commit = [&](const float4 (&L)[3][2], short* Ks, unsigned* Vs) {
#pragma unroll
        for (int k = 0; k < 3; ++k) {
            const int id = tid + 256 * k;
            const bool isK = id < 384;
            const int tt = isK ? id : id - 384;
            const int i = tt >> 2, o = tt & 3;
            if (isK) {
                BF8 u;
                u.h[0] = __float22bfloat162_rn(make_float2(L[k][0].x, L[k][0].y));
                u.h[1] = __float22bfloat162_rn(make_float2(L[k][0].z, L[k][0].w));
                u.h[2] = __float22bfloat162_rn(make_float2(L[k][1].x, L[k][1].y));
                u.h[3] = __float22bfloat162_rn(make_float2(L[k][1].z, L[k][1].w));
                *(s16x8*)&Ks[i * 32 + 8 * o] = u.v;
            } else {
                U32 w0, w1, w2, w3;
                w0.h = __float22bfloat162_rn(make_float2(L[k][0].x, L[k][1].x));
                w1.h = __float22bfloat162_rn(make_float2(L[k][0].y, L[k][1].y));
                w2.h = __float22bfloat162_rn(make_float2(L[k][0].z, L[k][1].z));
                w3.h = __float22bfloat162_rn(make_float2(L[k][0].w, L[k][1].w));
                *(uint4*)&Vs[i * VSTR + 4 * o] = make_uint4(w0.u, w1.u, w2.u, w3.u);
            }
        }
    };

    // ---- R9 compute core, parameterized by phase buffers ----
    auto computePhase = [&](const short* Ks, const unsigned* Vs, int sp,
                            const BF8& bqp, const float4& ga, const float4& gb,
                            unsigned long long mIp) {
        // QK^T: 3 MFMAs; S[blk][r] = S[key slot 16blk+4g+r][q]
        f32x4 S[3];
#pragma unroll
        for (int blk = 0; blk < 3; ++blk) {
            const s16x8 ak = *(const s16x8*)&Ks[(16 * w + 16 * blk + q) * 32 + 8 * g];
            S[blk] = MFMA16(ak, bqp.v, (f32x4){0.f, 0.f, 0.f, 0.f}, 0, 0, 0);
        }
        const unsigned long long vm = (0x1FFFFFULL << (q + 6)) & ~mIp;

        // max-free masked exp2 + pack to bf16 (1/sum deferred)
        float sm = 0.f;
        unsigned pk[3][2];
#pragma unroll
        for (int blk = 0; blk < 3; ++blk) {
            float e[4];
#pragma unroll
            for (int r = 0; r < 4; ++r) {
                const int j = 16 * blk + 4 * g + r;
                const float x = ((vm >> j) & 1ULL) ? S[blk][r] : -1e30f;
                e[r] = __builtin_amdgcn_exp2f(x);
                sm += e[r];
            }
            U32 a, b2;
            a.h  = __float22bfloat162_rn(make_float2(e[0], e[1]));
            b2.h = __float22bfloat162_rn(make_float2(e[2], e[3]));
            pk[blk][0] = a.u;
            pk[blk][1] = b2.u;
        }
        sm += __shfl_xor(sm, 16);
        sm += __shfl_xor(sm, 32);

        // PV (swapped): O^T = A(V^T) * B(P)
        f32x4 O0 = {0.f, 0.f, 0.f, 0.f}, O1 = {0.f, 0.f, 0.f, 0.f};
        {   // sb = 0: slots 0..31
            const int R = 16 * w;
            unsigned r0[4], r1[4];
#pragma unroll
            for (int jj = 0; jj < 4; ++jj) {
                r0[jj] = Vs[(R + 4 * g + jj) * VSTR + q];
                r1[jj] = Vs[(R + 16 + 4 * g + jj) * VSTR + q];
            }
            U4 A0, A1v;
            A0.u[0]  = __builtin_amdgcn_perm(r0[1], r0[0], 0x05040100u);
            A0.u[1]  = __builtin_amdgcn_perm(r0[3], r0[2], 0x05040100u);
            A0.u[2]  = __builtin_amdgcn_perm(r1[1], r1[0], 0x05040100u);
            A0.u[3]  = __builtin_amdgcn_perm(r1[3], r1[2], 0x05040100u);
            A1v.u[0] = __builtin_amdgcn_perm(r0[1], r0[0], 0x07060302u);
            A1v.u[1] = __builtin_amdgcn_perm(r0[3], r0[2], 0x07060302u);
            A1v.u[2] = __builtin_amdgcn_perm(r1[1], r1[0], 0x07060302u);
            A1v.u[3] = __builtin_amdgcn_perm(r1[3], r1[2], 0x07060302u);
            U4 Bp;
            Bp.u[0] = pk[0][0]; Bp.u[1] = pk[0][1];
            Bp.u[2] = pk[1][0]; Bp.u[3] = pk[1][1];
            O0 = MFMA16(A0.v,  Bp.v, O0, 0, 0, 0);
            O1 = MFMA16(A1v.v, Bp.v, O1, 0, 0, 0);
        }
        {   // sb = 1: slots 32..47 in k=0..3; k=4..7 zero on both operands
            const int R = 16 * w + 32;
            unsigned r0[4];
#pragma unroll
            for (int jj = 0; jj < 4; ++jj)
                r0[jj] = Vs[(R + 4 * g + jj) * VSTR + q];    // max row 95
            U4 A0, A1v;
            A0.u[0]  = __builtin_amdgcn_perm(r0[1], r0[0], 0x05040100u);
            A0.u[1]  = __builtin_amdgcn_perm(r0[3], r0[2], 0x05040100u);
            A0.u[2]  = 0u; A0.u[3] = 0u;
            A1v.u[0] = __builtin_amdgcn_perm(r0[1], r0[0], 0x07060302u);
            A1v.u[1] = __builtin_amdgcn_perm(r0[3], r0[2], 0x07060302u);
            A1v.u[2] = 0u; A1v.u[3] = 0u;
            U4 Bp;
            Bp.u[0] = pk[2][0]; Bp.u[1] = pk[2][1];
            Bp.u[2] = 0u;       Bp.u[3] = 0u;
            O0 = MFMA16(A0.v,  Bp.v, O0, 0, 0, 0);
            O1 = MFMA16(A1v.v, Bp.v, O1, 0, 0, 0);
        }

        // epilogue: lane(q,g) owns query sp+16w+q, ch {4g..} u {16+4g..}
        const float invq = 1.0f / sm;
        float4 o0, o1;
        o0.x = O0[0] * invq * ga.x;  o0.y = O0[1] * invq * ga.y;
        o0.z = O0[2] * invq * ga.z;  o0.w = O0[3] * invq * ga.w;
        o1.x = O1[0] * invq * gb.x;  o1.y = O1[1] * invq * gb.y;
        o1.z = O1[2] * invq * gb.z;  o1.w = O1[3] * invq * gb.w;
        float* obase = &out[((n * SEQ + sp + 16 * w + q) * HEADS + h) * 32];
        *(float4*)&obase[4 * g]      = o0;
        *(float4*)&obase[16 + 4 * g] = o1;
    };

    // ---- 2-phase schedule ----
    commit(ld[0], K_s[0], V_s[0]);
    __syncthreads();
    computePhase(K_s[0], V_s[0], s0, bq[0], gA[0], gB[0], mI[0]);
    commit(ld[1], K_s[1], V_s[1]);
    __syncthreads();
    computePhase(K_s[1], V_s[1], s0 + 64, bq[1], gA[1], gB[1], mI[1]);
}

extern "C" void kernel_launch(void* const* d_in, const int* in_sizes, int n_in,
                              void* d_out, int out_size, void* d_ws, size_t ws_size,
                              hipStream_t stream) {
    const float* Q = (const float*)d_in[0];
    const float* K = (const float*)d_in[1];
    const float* V = (const float*)d_in[2];
    const float* G = (const float*)d_in[3];
    const unsigned char* seqMask = (const unsigned char*)d_in[4];
    float* out = (float*)d_out;

    const int blocks = HEADS * BATCH * (SEQ / RPB);   // 512
    lwin_attn_kernel<<<blocks, 256, 0, stream>>>(Q, K, V, G, seqMask, out);
}

// Round 14
// 12.723 us; speedup vs baseline: 1.0371x; 1.0371x over previous
//
#include <hip/hip_runtime.h>
#include <hip/hip_bf16.h>
#include <math.h>

#define HEADS 8
#define BATCH 4
#define SEQ 2048
#define CDIM 32
#define WINDOW 10

#define RPB 64                 // rows per block = 4 waves x 16-row tiles
#define WBAND 48               // per-wave PRIVATE band rows: sw-16 .. sw+31
#define VSTR 20                // u32 stride of packed V rows (16 + 4 pad)

typedef float f32x4 __attribute__((ext_vector_type(4)));
typedef short s16x8 __attribute__((ext_vector_type(8)));
#define MFMA16 __builtin_amdgcn_mfma_f32_16x16x32_bf16

union BF8 { s16x8 v; __hip_bfloat162 h[4]; };
union U32 { __hip_bfloat162 h; unsigned u; };
union U4  { unsigned u[4]; s16x8 v; };

// Barrier-free design: each wave stages its own 48-row K/V band into a
// private LDS slice (the only sync is the wave's own ds_write->ds_read,
// ordered by lgkmcnt). 16 independent wave-pipelines per CU interleave so
// one wave's compute hides another's staging latency. Compute core = R9's
// verified swapped-PV bijection + packed V + max-free log2 softmax.
// Slot space: 48 slots j <-> key t = sw-16+j; valid iff j in [q+6,q+26]
// and not seq-masked.
__global__ __launch_bounds__(256) void lwin_attn_kernel(
    const float* __restrict__ Q, const float* __restrict__ K,
    const float* __restrict__ V, const float* __restrict__ G,
    const unsigned char* __restrict__ seqMask, float* __restrict__ out)
{
    __shared__ short    K_s[4][WBAND * 32];     // per-wave bf16 K band
    __shared__ unsigned V_s[4][WBAND * VSTR];   // per-wave packed V pairs

    // XCD-aware swizzle (1024 blocks, 128 per XCD chunk)
    const int d = blockIdx.x;
    const int b = (d & 7) * 128 + (d >> 3);

    const int hn = b >> 5;                      // h*BATCH + n (32 blocks per hn)
    const int s0 = (b & 31) * RPB;
    const int n  = hn & 3;
    const int h  = hn >> 2;
    const int base_hn = hn * SEQ * CDIM;

    const int tid  = threadIdx.x;
    const int w    = tid >> 6;                  // wave = tile index 0..3
    const int lane = tid & 63;
    const int q    = lane & 15;                 // query-in-tile / MFMA N-col
    const int g    = lane >> 4;                 // lane group

    const int sw = s0 + 16 * w;                 // tile first query row
    short*    Kw = K_s[w];
    unsigned* Vw = V_s[w];

    // ---- issue ALL global loads up front (deep MLP, wave-private) ----
    // staging: 48 rows x 4 octets = 192 K tasks + 192 V tasks per wave
    float4 kld[3][2], vld[3][2];
#pragma unroll
    for (int k = 0; k < 3; ++k) {
        const int id = 64 * k + lane;
        const int i  = id >> 2, o = id & 3;
        const int t  = sw - 16 + i;
        const int tc = min(max(t, 0), SEQ - 1);
        const float* kb = K + base_hn + tc * 32;
        const float* vb = V + base_hn + tc * 32;
        kld[k][0] = *(const float4*)&kb[8 * o];
        kld[k][1] = *(const float4*)&kb[8 * o + 4];
        vld[k][0] = *(const float4*)&vb[4 * o];
        vld[k][1] = *(const float4*)&vb[16 + 4 * o];
    }

    const int rowq = hn * SEQ + sw + q;
    const float sc = 0.17677669529663687f * 1.4426950408889634f; // 1/sqrt(32)*log2e
    const float4 q0 = *(const float4*)&Q[rowq * 32 + 8 * g];
    const float4 q1 = *(const float4*)&Q[rowq * 32 + 8 * g + 4];
    const float4 ga = *(const float4*)&G[rowq * 32 + 4 * g];
    const float4 gb = *(const float4*)&G[rowq * 32 + 16 + 4 * g];

    // ---- per-wave seqMask ballot: bit l = band row l invalid ----
    unsigned long long mI;
    {
        const int t  = sw - 16 + lane;
        const int tc = min(max(t, 0), SEQ - 1);
        const bool inval = (t < 0) || (t >= SEQ) || (seqMask[n * SEQ + tc] != 0);
        mI = __ballot(inval);
    }
    const unsigned long long vm = (0x1FFFFFULL << (q + 6)) & ~mI;

    // ---- Q B-fragment (scaled -> bf16) ----
    BF8 bq;
    bq.h[0] = __float22bfloat162_rn(make_float2(q0.x * sc, q0.y * sc));
    bq.h[1] = __float22bfloat162_rn(make_float2(q0.z * sc, q0.w * sc));
    bq.h[2] = __float22bfloat162_rn(make_float2(q1.x * sc, q1.y * sc));
    bq.h[3] = __float22bfloat162_rn(make_float2(q1.z * sc, q1.w * sc));

    // ---- commit staged rows to the wave-private LDS slice ----
#pragma unroll
    for (int k = 0; k < 3; ++k) {
        const int id = 64 * k + lane;
        const int i  = id >> 2, o = id & 3;
        BF8 uk;
        uk.h[0] = __float22bfloat162_rn(make_float2(kld[k][0].x, kld[k][0].y));
        uk.h[1] = __float22bfloat162_rn(make_float2(kld[k][0].z, kld[k][0].w));
        uk.h[2] = __float22bfloat162_rn(make_float2(kld[k][1].x, kld[k][1].y));
        uk.h[3] = __float22bfloat162_rn(make_float2(kld[k][1].z, kld[k][1].w));
        *(s16x8*)&Kw[i * 32 + 8 * o] = uk.v;
        U32 w0, w1, w2, w3;
        w0.h = __float22bfloat162_rn(make_float2(vld[k][0].x, vld[k][1].x));
        w1.h = __float22bfloat162_rn(make_float2(vld[k][0].y, vld[k][1].y));
        w2.h = __float22bfloat162_rn(make_float2(vld[k][0].z, vld[k][1].z));
        w3.h = __float22bfloat162_rn(make_float2(vld[k][0].w, vld[k][1].w));
        *(uint4*)&Vw[i * VSTR + 4 * o] = make_uint4(w0.u, w1.u, w2.u, w3.u);
    }
    // NO __syncthreads(): the compiler orders this wave's ds_write -> ds_read
    // (same arrays) via lgkmcnt; no cross-wave LDS dependencies exist.

    // ---- QK^T: 3 MFMAs; S[blk][r] = S[slot 16blk+4g+r][q] ----
    f32x4 S[3];
#pragma unroll
    for (int blk = 0; blk < 3; ++blk) {
        const s16x8 ak = *(const s16x8*)&Kw[(16 * blk + q) * 32 + 8 * g];
        S[blk] = MFMA16(ak, bq.v, (f32x4){0.f, 0.f, 0.f, 0.f}, 0, 0, 0);
    }

    // ---- max-free masked exp2 + pack to bf16 (1/sum deferred) ----
    float sm = 0.f;
    unsigned pk[3][2];
#pragma unroll
    for (int blk = 0; blk < 3; ++blk) {
        float e[4];
#pragma unroll
        for (int r = 0; r < 4; ++r) {
            const int j = 16 * blk + 4 * g + r;
            const float x = ((vm >> j) & 1ULL) ? S[blk][r] : -1e30f;
            e[r] = __builtin_amdgcn_exp2f(x);
            sm += e[r];
        }
        U32 a, b2;
        a.h  = __float22bfloat162_rn(make_float2(e[0], e[1]));
        b2.h = __float22bfloat162_rn(make_float2(e[2], e[3]));
        pk[blk][0] = a.u;
        pk[blk][1] = b2.u;
    }
    sm += __shfl_xor(sm, 16);
    sm += __shfl_xor(sm, 32);

    // ---- PV (swapped): O^T = A(V^T) * B(P) ----
    f32x4 O0 = {0.f, 0.f, 0.f, 0.f}, O1 = {0.f, 0.f, 0.f, 0.f};
    {   // sb = 0: slots 0..31
        unsigned r0[4], r1[4];
#pragma unroll
        for (int jj = 0; jj < 4; ++jj) {
            r0[jj] = Vw[(4 * g + jj) * VSTR + q];
            r1[jj] = Vw[(16 + 4 * g + jj) * VSTR + q];
        }
        U4 A0, A1v;
        A0.u[0]  = __builtin_amdgcn_perm(r0[1], r0[0], 0x05040100u);
        A0.u[1]  = __builtin_amdgcn_perm(r0[3], r0[2], 0x05040100u);
        A0.u[2]  = __builtin_amdgcn_perm(r1[1], r1[0], 0x05040100u);
        A0.u[3]  = __builtin_amdgcn_perm(r1[3], r1[2], 0x05040100u);
        A1v.u[0] = __builtin_amdgcn_perm(r0[1], r0[0], 0x07060302u);
        A1v.u[1] = __builtin_amdgcn_perm(r0[3], r0[2], 0x07060302u);
        A1v.u[2] = __builtin_amdgcn_perm(r1[1], r1[0], 0x07060302u);
        A1v.u[3] = __builtin_amdgcn_perm(r1[3], r1[2], 0x07060302u);
        U4 Bp;
        Bp.u[0] = pk[0][0]; Bp.u[1] = pk[0][1];
        Bp.u[2] = pk[1][0]; Bp.u[3] = pk[1][1];
        O0 = MFMA16(A0.v,  Bp.v, O0, 0, 0, 0);
        O1 = MFMA16(A1v.v, Bp.v, O1, 0, 0, 0);
    }
    {   // sb = 1: slots 32..47 in k=0..3; k=4..7 zero on both operands
        unsigned r0[4];
#pragma unroll
        for (int jj = 0; jj < 4; ++jj)
            r0[jj] = Vw[(32 + 4 * g + jj) * VSTR + q];      // max row 47
        U4 A0, A1v;
        A0.u[0]  = __builtin_amdgcn_perm(r0[1], r0[0], 0x05040100u);
        A0.u[1]  = __builtin_amdgcn_perm(r0[3], r0[2], 0x05040100u);
        A0.u[2]  = 0u; A0.u[3] = 0u;
        A1v.u[0] = __builtin_amdgcn_perm(r0[1], r0[0], 0x07060302u);
        A1v.u[1] = __builtin_amdgcn_perm(r0[3], r0[2], 0x07060302u);
        A1v.u[2] = 0u; A1v.u[3] = 0u;
        U4 Bp;
        Bp.u[0] = pk[2][0]; Bp.u[1] = pk[2][1];
        Bp.u[2] = 0u;       Bp.u[3] = 0u;
        O0 = MFMA16(A0.v,  Bp.v, O0, 0, 0, 0);
        O1 = MFMA16(A1v.v, Bp.v, O1, 0, 0, 0);
    }

    // ---- epilogue: lane(q,g) owns query sw+q, ch {4g..4g+3} u {16+4g..} ----
    const float invq = 1.0f / sm;
    float4 o0, o1;
    o0.x = O0[0] * invq * ga.x;  o0.y = O0[1] * invq * ga.y;
    o0.z = O0[2] * invq * ga.z;  o0.w = O0[3] * invq * ga.w;
    o1.x = O1[0] * invq * gb.x;  o1.y = O1[1] * invq * gb.y;
    o1.z = O1[2] * invq * gb.z;  o1.w = O1[3] * invq * gb.w;
    float* obase = &out[((n * SEQ + sw + q) * HEADS + h) * 32];
    *(float4*)&obase[4 * g]      = o0;
    *(float4*)&obase[16 + 4 * g] = o1;
}

extern "C" void kernel_launch(void* const* d_in, const int* in_sizes, int n_in,
                              void* d_out, int out_size, void* d_ws, size_t ws_size,
                              hipStream_t stream) {
    const float* Q = (const float*)d_in[0];
    const float* K = (const float*)d_in[1];
    const float* V = (const float*)d_in[2];
    const float* G = (const float*)d_in[3];
    const unsigned char* seqMask = (const unsigned char*)d_in[4];
    float* out = (float*)d_out;

    const int blocks = HEADS * BATCH * (SEQ / RPB);   // 1024
    lwin_attn_kernel<<<blocks, 256, 0, stream>>>(Q, K, V, G, seqMask, out);
}

// Round 15
// 12.640 us; speedup vs baseline: 1.0439x; 1.0066x over previous
//
#include <hip/hip_runtime.h>
#include <hip/hip_bf16.h>
#include <math.h>

#define HEADS 8
#define BATCH 4
#define SEQ 2048
#define CDIM 32
#define WINDOW 10

#define RPB 64                 // rows per block = 4 waves x 16-row MFMA tiles
#define VROWS 96               // band-row index space (rows 6..89 staged)
#define VSTR 20                // u32 stride of packed V rows (16 + 4 pad)

typedef float f32x4 __attribute__((ext_vector_type(4)));
typedef short s16x8 __attribute__((ext_vector_type(8)));
#define MFMA16 __builtin_amdgcn_mfma_f32_16x16x32_bf16

union BF8 { s16x8 v; __hip_bfloat162 h[4]; };
union U32 { __hip_bfloat162 h; unsigned u; };
union U4  { unsigned u[4]; s16x8 v; };

// R9 core (swapped-PV shared-bijection MFMA, packed V, max-free log2 softmax,
// per-wave ballot) with the staged halo trimmed to the true +-10 window:
// band rows 6..89 (keys s0-10..s0+73) are staged; rows 0..5 / 90..95 are never
// valid (slot j valid only for j in [q+6,q+26]). Unstaged K rows flow into
// masked-out scores (safe); unstaged V rows are zeroed (NaN*0=NaN in MFMA
// otherwise).
__global__ __launch_bounds__(256) void lwin_attn_kernel(
    const float* __restrict__ Q, const float* __restrict__ K,
    const float* __restrict__ V, const float* __restrict__ G,
    const unsigned char* __restrict__ seqMask, float* __restrict__ out)
{
    __shared__ short    K_s[VROWS * 32];        // bf16 K band, row-major
    __shared__ unsigned V_s[VROWS * VSTR];      // packed (ch c, ch c+16) pairs

    // XCD-aware swizzle (1024 blocks, 128 per XCD chunk)
    const int d = blockIdx.x;
    const int b = (d & 7) * 128 + (d >> 3);

    const int hn = b >> 5;                      // h*BATCH + n (32 blocks per hn)
    const int s0 = (b & 31) * RPB;
    const int n  = hn & 3;
    const int h  = hn >> 2;
    const int base_hn = hn * SEQ * CDIM;

    const int tid  = threadIdx.x;
    const int w    = tid >> 6;                  // wave = tile index 0..3
    const int lane = tid & 63;
    const int q    = lane & 15;                 // query-in-tile / MFMA N-col
    const int g    = lane >> 4;                 // lane group

    // ---- staging: 336 K tasks + 336 V tasks (rows 6..89) + 48 V-pad zeros ----
#pragma unroll
    for (int it = 0; it < 3; ++it) {
        const int task = tid + it * 256;
        if (task < 336) {                       // K: i = 6..89, octet o = 0..3
            const int i = 6 + (task >> 2), o = task & 3;
            const int t  = s0 - 16 + i;
            const int tc = min(max(t, 0), SEQ - 1);
            const float4 f0 = *(const float4*)&K[base_hn + tc * 32 + 8 * o];
            const float4 f1 = *(const float4*)&K[base_hn + tc * 32 + 8 * o + 4];
            BF8 u;
            u.h[0] = __float22bfloat162_rn(make_float2(f0.x, f0.y));
            u.h[1] = __float22bfloat162_rn(make_float2(f0.z, f0.w));
            u.h[2] = __float22bfloat162_rn(make_float2(f1.x, f1.y));
            u.h[3] = __float22bfloat162_rn(make_float2(f1.z, f1.w));
            *(s16x8*)&K_s[i * 32 + 8 * o] = u.v;
        } else if (task < 672) {                // V: i = 6..89, quad o = 0..3
            const int vt = task - 336;
            const int i = 6 + (vt >> 2), o = vt & 3;
            const int t  = s0 - 16 + i;
            const int tc = min(max(t, 0), SEQ - 1);
            const float4 f0 = *(const float4*)&V[base_hn + tc * 32 + 4 * o];
            const float4 f1 = *(const float4*)&V[base_hn + tc * 32 + 16 + 4 * o];
            U32 w0, w1, w2, w3;
            w0.h = __float22bfloat162_rn(make_float2(f0.x, f1.x));
            w1.h = __float22bfloat162_rn(make_float2(f0.y, f1.y));
            w2.h = __float22bfloat162_rn(make_float2(f0.z, f1.z));
            w3.h = __float22bfloat162_rn(make_float2(f0.w, f1.w));
            *(uint4*)&V_s[i * VSTR + 4 * o] = make_uint4(w0.u, w1.u, w2.u, w3.u);
        } else if (task < 720) {                // zero V pad rows 0..5, 90..95
            const int zt = task - 672;
            const int zr = zt >> 2, o = zt & 3;
            const int i = (zr < 6) ? zr : 84 + zr;
            *(uint4*)&V_s[i * VSTR + 4 * o] = make_uint4(0u, 0u, 0u, 0u);
        }
    }

    const int sw   = s0 + 16 * w;
    const int rowq = hn * SEQ + sw + q;

    // ---- Q B-fragment (scaled, bf16) + G (prefetched for epilogue) ----
    const float sc = 0.17677669529663687f * 1.4426950408889634f; // 1/sqrt(32)*log2e
    const float4 q0 = *(const float4*)&Q[rowq * 32 + 8 * g];
    const float4 q1 = *(const float4*)&Q[rowq * 32 + 8 * g + 4];
    BF8 bq;
    bq.h[0] = __float22bfloat162_rn(make_float2(q0.x * sc, q0.y * sc));
    bq.h[1] = __float22bfloat162_rn(make_float2(q0.z * sc, q0.w * sc));
    bq.h[2] = __float22bfloat162_rn(make_float2(q1.x * sc, q1.y * sc));
    bq.h[3] = __float22bfloat162_rn(make_float2(q1.z * sc, q1.w * sc));
    const float4 ga = *(const float4*)&G[rowq * 32 + 4 * g];
    const float4 gb = *(const float4*)&G[rowq * 32 + 16 + 4 * g];

    // ---- per-wave seqMask ballot: bit l = band row 16w+l invalid ----
    unsigned long long mI;
    {
        const int t  = sw - 16 + lane;
        const int tc = min(max(t, 0), SEQ - 1);
        const bool inval = (t < 0) || (t >= SEQ) || (seqMask[n * SEQ + tc] != 0);
        mI = __ballot(inval);
    }
    const unsigned long long vm = (0x1FFFFFULL << (q + 6)) & ~mI;

    __syncthreads();

    // ---- QK^T: 3 MFMAs; S[blk][r] = S[key slot 16blk+4g+r][q] ----
    f32x4 S[3];
#pragma unroll
    for (int blk = 0; blk < 3; ++blk) {
        const s16x8 ak = *(const s16x8*)&K_s[(16 * w + 16 * blk + q) * 32 + 8 * g];
        S[blk] = MFMA16(ak, bq.v, (f32x4){0.f, 0.f, 0.f, 0.f}, 0, 0, 0);
    }

    // ---- max-free masked exp2 + pack to bf16 (1/sum deferred) ----
    float sm = 0.f;
    unsigned pk[3][2];
#pragma unroll
    for (int blk = 0; blk < 3; ++blk) {
        float e[4];
#pragma unroll
        for (int r = 0; r < 4; ++r) {
            const int j = 16 * blk + 4 * g + r;
            const float x = ((vm >> j) & 1ULL) ? S[blk][r] : -1e30f;
            e[r] = __builtin_amdgcn_exp2f(x);
            sm += e[r];
        }
        U32 a, b2;
        a.h  = __float22bfloat162_rn(make_float2(e[0], e[1]));
        b2.h = __float22bfloat162_rn(make_float2(e[2], e[3]));
        pk[blk][0] = a.u;
        pk[blk][1] = b2.u;
    }
    sm += __shfl_xor(sm, 16);
    sm += __shfl_xor(sm, 32);

    // ---- PV (swapped): O^T = A(V^T) * B(P) ----
    f32x4 O0 = {0.f, 0.f, 0.f, 0.f}, O1 = {0.f, 0.f, 0.f, 0.f};
    {   // sb = 0: slots 0..31
        const int R = 16 * w;
        unsigned r0[4], r1[4];
#pragma unroll
        for (int jj = 0; jj < 4; ++jj) {
            r0[jj] = V_s[(R + 4 * g + jj) * VSTR + q];
            r1[jj] = V_s[(R + 16 + 4 * g + jj) * VSTR + q];
        }
        U4 A0, A1v;
        A0.u[0]  = __builtin_amdgcn_perm(r0[1], r0[0], 0x05040100u);
        A0.u[1]  = __builtin_amdgcn_perm(r0[3], r0[2], 0x05040100u);
        A0.u[2]  = __builtin_amdgcn_perm(r1[1], r1[0], 0x05040100u);
        A0.u[3]  = __builtin_amdgcn_perm(r1[3], r1[2], 0x05040100u);
        A1v.u[0] = __builtin_amdgcn_perm(r0[1], r0[0], 0x07060302u);
        A1v.u[1] = __builtin_amdgcn_perm(r0[3], r0[2], 0x07060302u);
        A1v.u[2] = __builtin_amdgcn_perm(r1[1], r1[0], 0x07060302u);
        A1v.u[3] = __builtin_amdgcn_perm(r1[3], r1[2], 0x07060302u);
        U4 Bp;
        Bp.u[0] = pk[0][0]; Bp.u[1] = pk[0][1];
        Bp.u[2] = pk[1][0]; Bp.u[3] = pk[1][1];
        O0 = MFMA16(A0.v,  Bp.v, O0, 0, 0, 0);
        O1 = MFMA16(A1v.v, Bp.v, O1, 0, 0, 0);
    }
    {   // sb = 1: slots 32..47 in k=0..3; k=4..7 zero on both operands
        const int R = 16 * w + 32;
        unsigned r0[4];
#pragma unroll
        for (int jj = 0; jj < 4; ++jj)
            r0[jj] = V_s[(R + 4 * g + jj) * VSTR + q];      // max row 95 (pad=0)
        U4 A0, A1v;
        A0.u[0]  = __builtin_amdgcn_perm(r0[1], r0[0], 0x05040100u);
        A0.u[1]  = __builtin_amdgcn_perm(r0[3], r0[2], 0x05040100u);
        A0.u[2]  = 0u; A0.u[3] = 0u;
        A1v.u[0] = __builtin_amdgcn_perm(r0[1], r0[0], 0x07060302u);
        A1v.u[1] = __builtin_amdgcn_perm(r0[3], r0[2], 0x07060302u);
        A1v.u[2] = 0u; A1v.u[3] = 0u;
        U4 Bp;
        Bp.u[0] = pk[2][0]; Bp.u[1] = pk[2][1];
        Bp.u[2] = 0u;       Bp.u[3] = 0u;
        O0 = MFMA16(A0.v,  Bp.v, O0, 0, 0, 0);
        O1 = MFMA16(A1v.v, Bp.v, O1, 0, 0, 0);
    }

    // ---- epilogue: lane(q,g) owns query sw+q, ch {4g..4g+3} u {16+4g..} ----
    const float invq = 1.0f / sm;
    float4 o0, o1;
    o0.x = O0[0] * invq * ga.x;  o0.y = O0[1] * invq * ga.y;
    o0.z = O0[2] * invq * ga.z;  o0.w = O0[3] * invq * ga.w;
    o1.x = O1[0] * invq * gb.x;  o1.y = O1[1] * invq * gb.y;
    o1.z = O1[2] * invq * gb.z;  o1.w = O1[3] * invq * gb.w;
    float* obase = &out[((n * SEQ + sw + q) * HEADS + h) * 32];
    *(float4*)&obase[4 * g]      = o0;
    *(float4*)&obase[16 + 4 * g] = o1;
}

extern "C" void kernel_launch(void* const* d_in, const int* in_sizes, int n_in,
                              void* d_out, int out_size, void* d_ws, size_t ws_size,
                              hipStream_t stream) {
    const float* Q = (const float*)d_in[0];
    const float* K = (const float*)d_in[1];
    const float* V = (const float*)d_in[2];
    const float* G = (const float*)d_in[3];
    const unsigned char* seqMask = (const unsigned char*)d_in[4];
    float* out = (float*)d_out;

    const int blocks = HEADS * BATCH * (SEQ / RPB);   // 1024
    lwin_attn_kernel<<<blocks, 256, 0, stream>>>(Q, K, V, G, seqMask, out);
}

// Round 16
// 12.327 us; speedup vs baseline: 1.0705x; 1.0254x over previous
//
#include <hip/hip_runtime.h>
#include <hip/hip_bf16.h>
#include <math.h>

#define HEADS 8
#define BATCH 4
#define SEQ 2048
#define CDIM 32
#define WINDOW 10

#define RPB 64                 // rows per block = 4 waves x 16-row MFMA tiles
#define VROWS 96               // V band rows staged
#define VSTR 20                // u32 stride of packed V rows (16 + 4 pad)

typedef float f32x4 __attribute__((ext_vector_type(4)));
typedef short s16x8 __attribute__((ext_vector_type(8)));
#define MFMA16 __builtin_amdgcn_mfma_f32_16x16x32_bf16

union BF8 { s16x8 v; __hip_bfloat162 h[4]; };
union U32 { __hip_bfloat162 h; unsigned u; };
union U4  { unsigned u[4]; s16x8 v; };

// R9 configuration (best measured: 11.96 us). Per-wave 16-row tile; 48 key
// slots j <-> key t = sw-16+j; slot j valid for query q iff j in [q+6,q+26]
// and key not seq-masked.
// QK^T: C[key][q] = mfma(A=K from LDS, B=Q).
// PV (operand-swapped): O^T[ch][q] = mfma(A=V^T from LDS, B=P in-lane) with
// shared slot->k bijection f(g,j) = 4g+j / 16+4g+(j-4): P needs no
// cross-lane relayout. Max-free log2-domain softmax; 1/sum in epilogue.
__global__ __launch_bounds__(256) void lwin_attn_kernel(
    const float* __restrict__ Q, const float* __restrict__ K,
    const float* __restrict__ V, const float* __restrict__ G,
    const unsigned char* __restrict__ seqMask, float* __restrict__ out)
{
    __shared__ short    K_s[VROWS * 32];        // bf16 K band, row-major [96][32]
    __shared__ unsigned V_s[VROWS * VSTR];      // packed (ch c, ch c+16) bf16 pairs

    // XCD-aware swizzle (1024 blocks, 128 per XCD chunk)
    const int d = blockIdx.x;
    const int b = (d & 7) * 128 + (d >> 3);

    const int hn = b >> 5;                      // h*BATCH + n (32 blocks per hn)
    const int s0 = (b & 31) * RPB;
    const int n  = hn & 3;
    const int h  = hn >> 2;
    const int base_hn = hn * SEQ * CDIM;

    const int tid  = threadIdx.x;
    const int w    = tid >> 6;                  // wave = tile index 0..3
    const int lane = tid & 63;
    const int q    = lane & 15;                 // query-in-tile / MFMA N-col
    const int g    = lane >> 4;                 // lane group

    // ---- stage K (384 tasks, row-major bf16) and V (448 tasks, packed) ----
#pragma unroll
    for (int it = 0; it < 4; ++it) {
        const int task = tid + it * 256;
        if (task < 384) {                       // K: i = 0..95, octet o = 0..3
            const int i = task >> 2, o = task & 3;
            const int t  = s0 - 16 + i;
            const int tc = min(max(t, 0), SEQ - 1);
            const float4 f0 = *(const float4*)&K[base_hn + tc * 32 + 8 * o];
            const float4 f1 = *(const float4*)&K[base_hn + tc * 32 + 8 * o + 4];
            BF8 u;
            u.h[0] = __float22bfloat162_rn(make_float2(f0.x, f0.y));
            u.h[1] = __float22bfloat162_rn(make_float2(f0.z, f0.w));
            u.h[2] = __float22bfloat162_rn(make_float2(f1.x, f1.y));
            u.h[3] = __float22bfloat162_rn(make_float2(f1.z, f1.w));
            *(s16x8*)&K_s[i * 32 + 8 * o] = u.v;
        } else if (task < 384 + 448) {          // V: i = 0..111 clamped to 95
            const int vt = task - 384;
            const int i = min(vt >> 2, VROWS - 1), o = vt & 3;
            const int t  = s0 - 16 + (vt >> 2);
            const int tc = min(max(t, 0), SEQ - 1);
            const float4 f0 = *(const float4*)&V[base_hn + tc * 32 + 4 * o];
            const float4 f1 = *(const float4*)&V[base_hn + tc * 32 + 16 + 4 * o];
            U32 w0, w1, w2, w3;
            w0.h = __float22bfloat162_rn(make_float2(f0.x, f1.x));
            w1.h = __float22bfloat162_rn(make_float2(f0.y, f1.y));
            w2.h = __float22bfloat162_rn(make_float2(f0.z, f1.z));
            w3.h = __float22bfloat162_rn(make_float2(f0.w, f1.w));
            *(uint4*)&V_s[i * VSTR + 4 * o] = make_uint4(w0.u, w1.u, w2.u, w3.u);
        }
    }

    const int sw   = s0 + 16 * w;
    const int rowq = hn * SEQ + sw + q;

    // ---- Q B-fragment (scaled, bf16) + G (prefetched for epilogue) ----
    const float sc = 0.17677669529663687f * 1.4426950408889634f; // 1/sqrt(32)*log2e
    const float4 q0 = *(const float4*)&Q[rowq * 32 + 8 * g];
    const float4 q1 = *(const float4*)&Q[rowq * 32 + 8 * g + 4];
    BF8 bq;
    bq.h[0] = __float22bfloat162_rn(make_float2(q0.x * sc, q0.y * sc));
    bq.h[1] = __float22bfloat162_rn(make_float2(q0.z * sc, q0.w * sc));
    bq.h[2] = __float22bfloat162_rn(make_float2(q1.x * sc, q1.y * sc));
    bq.h[3] = __float22bfloat162_rn(make_float2(q1.z * sc, q1.w * sc));
    const float4 ga = *(const float4*)&G[rowq * 32 + 4 * g];
    const float4 gb = *(const float4*)&G[rowq * 32 + 16 + 4 * g];

    // ---- per-wave seqMask ballot: bit l = band row 16w+l invalid ----
    unsigned long long mI;
    {
        const int t  = sw - 16 + lane;
        const int tc = min(max(t, 0), SEQ - 1);
        const bool inval = (t < 0) || (t >= SEQ) || (seqMask[n * SEQ + tc] != 0);
        mI = __ballot(inval);
    }
    const unsigned long long vm = (0x1FFFFFULL << (q + 6)) & ~mI;

    __syncthreads();

    // ---- QK^T: 3 MFMAs; S[blk][r] = S[key slot 16blk+4g+r][q] ----
    f32x4 S[3];
#pragma unroll
    for (int blk = 0; blk < 3; ++blk) {
        const s16x8 ak = *(const s16x8*)&K_s[(16 * w + 16 * blk + q) * 32 + 8 * g];
        S[blk] = MFMA16(ak, bq.v, (f32x4){0.f, 0.f, 0.f, 0.f}, 0, 0, 0);
    }

    // ---- max-free masked exp2 + pack to bf16 (1/sum deferred) ----
    float sm = 0.f;
    unsigned pk[3][2];
#pragma unroll
    for (int blk = 0; blk < 3; ++blk) {
        float e[4];
#pragma unroll
        for (int r = 0; r < 4; ++r) {
            const int j = 16 * blk + 4 * g + r;
            const float x = ((vm >> j) & 1ULL) ? S[blk][r] : -1e30f;
            e[r] = __builtin_amdgcn_exp2f(x);
            sm += e[r];
        }
        U32 a, b2;
        a.h  = __float22bfloat162_rn(make_float2(e[0], e[1]));
        b2.h = __float22bfloat162_rn(make_float2(e[2], e[3]));
        pk[blk][0] = a.u;
        pk[blk][1] = b2.u;
    }
    sm += __shfl_xor(sm, 16);
    sm += __shfl_xor(sm, 32);

    // ---- PV (swapped): O^T = A(V^T) * B(P) ----
    f32x4 O0 = {0.f, 0.f, 0.f, 0.f}, O1 = {0.f, 0.f, 0.f, 0.f};
    {   // sb = 0: slots 0..31
        const int R = 16 * w;
        unsigned r0[4], r1[4];
#pragma unroll
        for (int jj = 0; jj < 4; ++jj) {
            r0[jj] = V_s[(R + 4 * g + jj) * VSTR + q];
            r1[jj] = V_s[(R + 16 + 4 * g + jj) * VSTR + q];
        }
        U4 A0, A1v;
        A0.u[0]  = __builtin_amdgcn_perm(r0[1], r0[0], 0x05040100u);
        A0.u[1]  = __builtin_amdgcn_perm(r0[3], r0[2], 0x05040100u);
        A0.u[2]  = __builtin_amdgcn_perm(r1[1], r1[0], 0x05040100u);
        A0.u[3]  = __builtin_amdgcn_perm(r1[3], r1[2], 0x05040100u);
        A1v.u[0] = __builtin_amdgcn_perm(r0[1], r0[0], 0x07060302u);
        A1v.u[1] = __builtin_amdgcn_perm(r0[3], r0[2], 0x07060302u);
        A1v.u[2] = __builtin_amdgcn_perm(r1[1], r1[0], 0x07060302u);
        A1v.u[3] = __builtin_amdgcn_perm(r1[3], r1[2], 0x07060302u);
        U4 Bp;
        Bp.u[0] = pk[0][0]; Bp.u[1] = pk[0][1];
        Bp.u[2] = pk[1][0]; Bp.u[3] = pk[1][1];
        O0 = MFMA16(A0.v,  Bp.v, O0, 0, 0, 0);
        O1 = MFMA16(A1v.v, Bp.v, O1, 0, 0, 0);
    }
    {   // sb = 1: slots 32..47 in k=0..3; k=4..7 zero on both operands
        const int R = 16 * w + 32;
        unsigned r0[4];
#pragma unroll
        for (int jj = 0; jj < 4; ++jj)
            r0[jj] = V_s[(R + 4 * g + jj) * VSTR + q];      // max row 95
        U4 A0, A1v;
        A0.u[0]  = __builtin_amdgcn_perm(r0[1], r0[0], 0x05040100u);
        A0.u[1]  = __builtin_amdgcn_perm(r0[3], r0[2], 0x05040100u);
        A0.u[2]  = 0u; A0.u[3] = 0u;
        A1v.u[0] = __builtin_amdgcn_perm(r0[1], r0[0], 0x07060302u);
        A1v.u[1] = __builtin_amdgcn_perm(r0[3], r0[2], 0x07060302u);
        A1v.u[2] = 0u; A1v.u[3] = 0u;
        U4 Bp;
        Bp.u[0] = pk[2][0]; Bp.u[1] = pk[2][1];
        Bp.u[2] = 0u;       Bp.u[3] = 0u;
        O0 = MFMA16(A0.v,  Bp.v, O0, 0, 0, 0);
        O1 = MFMA16(A1v.v, Bp.v, O1, 0, 0, 0);
    }

    // ---- epilogue: lane(q,g) owns query sw+q, ch {4g..4g+3} u {16+4g..} ----
    const float invq = 1.0f / sm;
    float4 o0, o1;
    o0.x = O0[0] * invq * ga.x;  o0.y = O0[1] * invq * ga.y;
    o0.z = O0[2] * invq * ga.z;  o0.w = O0[3] * invq * ga.w;
    o1.x = O1[0] * invq * gb.x;  o1.y = O1[1] * invq * gb.y;
    o1.z = O1[2] * invq * gb.z;  o1.w = O1[3] * invq * gb.w;
    float* obase = &out[((n * SEQ + sw + q) * HEADS + h) * 32];
    *(float4*)&obase[4 * g]      = o0;
    *(float4*)&obase[16 + 4 * g] = o1;
}

extern "C" void kernel_launch(void* const* d_in, const int* in_sizes, int n_in,
                              void* d_out, int out_size, void* d_ws, size_t ws_size,
                              hipStream_t stream) {
    const float* Q = (const float*)d_in[0];
    const float* K = (const float*)d_in[1];
    const float* V = (const float*)d_in[2];
    const float* G = (const float*)d_in[3];
    const unsigned char* seqMask = (const unsigned char*)d_in[4];
    float* out = (float*)d_out;

    const int blocks = HEADS * BATCH * (SEQ / RPB);   // 1024
    lwin_attn_kernel<<<blocks, 256, 0, stream>>>(Q, K, V, G, seqMask, out);
}